// Round 12
// baseline (2967.235 us; speedup 1.0000x reference)
//
#include <hip/hip_runtime.h>
#include <cstdint>
#include <cstddef>

#define TOKENS 131072      // B*T = 512*256
#define B_BATCH 512
#define T_SEQ 256
#define C_DIM 512
#define H_HEADS 4
#define HS_DIM 128
#define FF_DIM 2048
#define EPS_RMS 1e-8f
#define SM_SCALE 0.044194173824159216f   // 512^-0.5

typedef short bf16x8 __attribute__((ext_vector_type(8)));
typedef float f32x4 __attribute__((ext_vector_type(4)));
typedef unsigned short ushort_t;

__device__ __forceinline__ ushort_t f2bf(float f) {
    uint32_t u = __builtin_bit_cast(uint32_t, f);
    u += 0x7FFFu + ((u >> 16) & 1u);   // round-to-nearest-even
    return (ushort_t)(u >> 16);
}

__device__ __forceinline__ float bf2f(ushort_t u) {
    return __builtin_bit_cast(float, (uint32_t)u << 16);
}

// tanh-form GELU: |gelu_tanh - gelu_erf| <= ~3e-3 absolute; validated r7/r10
// (absmax unchanged at 0.03125).
__device__ __forceinline__ float gelu_f(float x) {
    float u = 0.7978845608028654f * x + 0.035677408136300125f * (x * x * x);
    float e = __expf(2.0f * u);                 // inf-safe: e=inf -> t=1
    float t = 1.0f - 2.0f / (1.0f + e);         // tanh(u)
    return 0.5f * x * (1.0f + t);
}

// async global->LDS, 16B/lane. Dest must be wave-uniform; HW adds lane*16.
__device__ __forceinline__ void stage8k(ushort_t* lds, const ushort_t* g) {
    __builtin_amdgcn_global_load_lds(
        (const __attribute__((address_space(1))) uint32_t*)g,
        (__attribute__((address_space(3))) uint32_t*)lds,
        16, 0, 0);
}

// ---------------------------------------------------------------------------
// Weight prep: fp32 -> bf16, transposed to N x K row-major
// ---------------------------------------------------------------------------
__global__ void prep_qkv(const float* __restrict__ Wq, const float* __restrict__ Wk,
                         const float* __restrict__ Wv, ushort_t* __restrict__ WqkvT) {
    int idx = blockIdx.x * 256 + threadIdx.x;       // over 1536*512
    if (idx >= 1536 * 512) return;
    int n = idx >> 9;
    int k = idx & 511;
    int h = (n & 511) >> 7;
    int d = n & 127;
    float v;
    size_t s = ((size_t)h * 512 + k) * 128 + d;     // (H,C,HS)
    if (n < 512)       v = Wq[s];
    else if (n < 1024) v = Wk[s];
    else               v = Wv[s];
    WqkvT[idx] = f2bf(v);
}

__global__ void prep_bias(const float* __restrict__ bk, float* __restrict__ bias1536) {
    int n = blockIdx.x * 256 + threadIdx.x;
    if (n >= 1536) return;
    bias1536[n] = (n >= 512 && n < 1024) ? bk[n - 512] : 0.0f;   // bk flat (H,HS)
}

__global__ void prep_proj(const float* __restrict__ Wproj, ushort_t* __restrict__ WprojT) {
    int idx = blockIdx.x * 256 + threadIdx.x;       // over 512*512
    if (idx >= 512 * 512) return;
    int n = idx >> 9, k = idx & 511;
    WprojT[idx] = f2bf(Wproj[(size_t)k * 512 + n]);
}

__global__ void prep_wi(const float* __restrict__ Wi, ushort_t* __restrict__ WiT) {
    int idx = blockIdx.x * 256 + threadIdx.x;       // over 2*2048*512
    if (idx >= 2 * 2048 * 512) return;
    int b = idx >> 20;
    int rem = idx & 1048575;
    int f = rem >> 9, c = rem & 511;                // WiT[b*2048+f][c] = [4096][512]
    WiT[idx] = f2bf(Wi[((size_t)b * 512 + c) * 2048 + f]);
}

// WoT2[c][br*2048+f] = 0.5 * Wo[br][f][c]  -> [512][4096] row-major over K=4096
__global__ void prep_wo(const float* __restrict__ Wo, ushort_t* __restrict__ WoT2) {
    int idx = blockIdx.x * 256 + threadIdx.x;       // over 512*4096
    if (idx >= 512 * 4096) return;
    int c  = idx >> 12;
    int n2 = idx & 4095;
    int br = n2 >> 11;
    int f  = n2 & 2047;
    WoT2[idx] = f2bf(0.5f * Wo[(((size_t)br * 2048 + f) * 512) + c]);
}

// ---------------------------------------------------------------------------
// RMSNorm: one wave per token (512 floats, 8/lane); bf16 out only.
// ---------------------------------------------------------------------------
__global__ __launch_bounds__(256) void rmsnorm_kernel(const float* __restrict__ in,
                                                      const float* __restrict__ wptr,
                                                      ushort_t* __restrict__ outb) {
    const int lane = threadIdx.x & 63;
    const int wave = threadIdx.x >> 6;
    const size_t token = (size_t)blockIdx.x * 4 + wave;
    const float* row = in + token * 512;
    float4 v0 = *(const float4*)(row + lane * 8);
    float4 v1 = *(const float4*)(row + lane * 8 + 4);
    float ss = v0.x*v0.x + v0.y*v0.y + v0.z*v0.z + v0.w*v0.w
             + v1.x*v1.x + v1.y*v1.y + v1.z*v1.z + v1.w*v1.w;
    #pragma unroll
    for (int d = 32; d; d >>= 1) ss += __shfl_xor(ss, d);
    float scale = wptr[0] * rsqrtf(ss * (1.0f / 512.0f) + EPS_RMS);
    float vals[8] = {v0.x, v0.y, v0.z, v0.w, v1.x, v1.y, v1.z, v1.w};
    union { ushort_t us[8]; uint4 u4; } pk;
    #pragma unroll
    for (int i = 0; i < 8; i++) pk.us[i] = f2bf(vals[i] * scale);
    *(uint4*)(outb + token * 512 + lane * 8) = pk.u4;
}

// ---------------------------------------------------------------------------
// GEMM 128x128, BK=32, triple-buffered counted-vmcnt, 48KB LDS -> 3 blocks/CU.
// C[M,N] = A[M,K] * Bt[N,K]^T (bf16, row-major over K). 4 waves (2M x 2N),
// per-wave C = 64x64 (acc 64 VGPR), 16 MFMA + 8 ds_read_b128 per K-tile.
//
// r12 rationale: r5-r11 proved the 256²/128KB barrier-lockstep schedule is
// pinned at ~25% MfmaUtil because LD-phase and MFMA-phase of the SINGLE
// resident block strictly alternate. Here 3 blocks/CU interleave: block A's
// MFMA overlaps block B's ds_reads/stages (m114 cross-wave overlap).
//
// Per K-tile body (ONE barrier):
//   stage(t+2) -> buf[(t+2)%3] (4 global_load_lds)
//   8 ds_read (swizzled) ; 16 MFMA (setprio-wrapped)
//   lgkmcnt(0) (own reads retired)  vmcnt(4) (tile t+1 landed)  s_barrier
// RAW: tile t drained by iter t-1's vmcnt(4) (fixed 4 issues/body; prologue
// stage(0),stage(1),vmcnt(4) establishes the invariant). WAR: stage(t+2)
// targets the buffer last read at iter t-1, retired before that barrier.
// Tails clamp SOURCE tile; clamped writes land in buffers never read again.
//
// LDS swizzle (64B rows = 4 granules of 16B): LDS(row,slot) holds global
// granule slot ^ ((row>>2)&3). Staged linear-dest + pre-swizzled source
// (lane granule (l&3)^((l>>4)&3); wave row-base mult of 16 -> lane-constant).
// Read slot = q ^ ((r16>>2)&3): 8 lanes per 4-bank group = 2 lanes/bank ->
// conflict-free (m136: 2-way free).
// MODE 0: Cb = bf16(acc + bias[c])       MODE 1: Cf = acc + bias[c] + X(f32)
// MODE 2: Cb = bf16(gelu(acc))           MODE 3: Cf = bf2f(Xb) + acc
// ---------------------------------------------------------------------------
template<int MODE>
__global__ __launch_bounds__(256) void gemm128(
    const ushort_t* __restrict__ A, const ushort_t* __restrict__ Bt,
    float* Cf, ushort_t* __restrict__ Cb,
    const float* __restrict__ bias, const float* __restrict__ X,
    const ushort_t* __restrict__ Xb,
    int N, int K)
{
    __shared__ __align__(16) ushort_t S[3][2][128 * 32];   // 48 KB
    const int tid  = threadIdx.x;
    const int lane = tid & 63;
    const int wave = tid >> 6;         // 0..3
    const int wm = wave >> 1;          // 0..1
    const int wn = wave & 1;           // 0..1

    // XCD-chunked bijective swizzle (nwg % 8 == 0 for all our grids)
    const int nwg  = (int)gridDim.x;
    const int orig = (int)blockIdx.x;
    const int wgid = (orig & 7) * (nwg >> 3) + (orig >> 3);
    const int gx   = N >> 7;
    const int bm = (wgid / gx) << 7;
    const int bn = (wgid % gx) << 7;

    const int NT = K >> 5;             // K-tiles of 32 (16 or 128 here)

    // staging source granule: (l&3) ^ ((l>>4)&3), in elements
    const int srcg = (((lane & 3) ^ ((lane >> 4) & 3)) << 3);

    // stage tile ts (A and B) into buffer sb: 4 wave-issues (A x2, B x2)
    auto stage = [&](int sb, int ts) {
        int tc = ts < NT ? ts : NT - 1;
        const int ko = tc << 5;
        #pragma unroll
        for (int i = 0; i < 2; i++) {
            const int rb = (wave * 2 + i) * 16;        // rows [rb, rb+16)
            stage8k(&S[sb][0][rb * 32],
                    A + (size_t)(bm + rb + (lane >> 2)) * K + ko + srcg);
            stage8k(&S[sb][1][rb * 32],
                    Bt + (size_t)(bn + rb + (lane >> 2)) * K + ko + srcg);
        }
    };

    const int r16 = lane & 15;
    const int q   = lane >> 4;
    const int ge  = ((q ^ ((r16 >> 2) & 3)) << 3);     // swizzled slot, elems
    const int aBase = (wm * 64 + r16) * 32 + ge;       // + mf*512
    const int bBase = (wn * 64 + r16) * 32 + ge;       // + nf*512

    f32x4 acc[4][4] = {};
    bf16x8 af[4], bf[4];

    // prologue: tiles 0,1 staged; vmcnt(4) -> tile0 done, tile1 in flight
    stage(0, 0);
    stage(1, 1);
    asm volatile("s_waitcnt vmcnt(4)" ::: "memory");
    __builtin_amdgcn_s_barrier();

    int cur = 0;
    for (int t = 0; t < NT; ++t) {
        int nxt = cur + 2; if (nxt >= 3) nxt -= 3;
        stage(nxt, t + 2);
        #pragma unroll
        for (int mf = 0; mf < 4; mf++)
            af[mf] = *(const bf16x8*)&S[cur][0][aBase + mf * 512];
        #pragma unroll
        for (int nf = 0; nf < 4; nf++)
            bf[nf] = *(const bf16x8*)&S[cur][1][bBase + nf * 512];
        __builtin_amdgcn_s_setprio(1);
        #pragma unroll
        for (int mf = 0; mf < 4; mf++)
            #pragma unroll
            for (int nf = 0; nf < 4; nf++)
                acc[mf][nf] = __builtin_amdgcn_mfma_f32_16x16x32_bf16(
                    af[mf], bf[nf], acc[mf][nf], 0, 0, 0);
        __builtin_amdgcn_s_setprio(0);
        asm volatile("s_waitcnt lgkmcnt(0)\n\ts_waitcnt vmcnt(4)" ::: "memory");
        __builtin_amdgcn_s_barrier();
        cur = (cur == 2) ? 0 : cur + 1;
    }

    #pragma unroll
    for (int mf = 0; mf < 4; mf++) {
        #pragma unroll
        for (int nf = 0; nf < 4; nf++) {
            #pragma unroll
            for (int j = 0; j < 4; j++) {
                int r = bm + wm * 64 + mf * 16 + q * 4 + j;
                int c = bn + wn * 64 + nf * 16 + r16;
                float v = acc[mf][nf][j];
                size_t idx = (size_t)r * N + c;
                if (MODE == 0)      { Cb[idx] = f2bf(v + bias[c]); }
                else if (MODE == 1) { Cf[idx] = v + bias[c] + X[idx]; }
                else if (MODE == 2) { Cb[idx] = f2bf(gelu_f(v)); }
                else                { Cf[idx] = bf2f(Xb[idx]) + v; }
            }
        }
    }
}

// ---------------------------------------------------------------------------
// Fused causal attention, flash-style (online softmax). Unchanged.
// ---------------------------------------------------------------------------
__global__ __launch_bounds__(256) void attn_kernel(const ushort_t* __restrict__ QKV,
                                                   ushort_t* __restrict__ Ao) {
    __shared__ __align__(16) ushort_t Ks[32 * 136];
    __shared__ __align__(16) ushort_t VsT[128 * 40];
    __shared__ __align__(16) ushort_t Ps[4][16 * 40];
    const int tid  = threadIdx.x;
    const int lane = tid & 63;
    const int wave = tid >> 6;
    const int qtile = blockIdx.x;                 // 0..3
    const int bh = blockIdx.y;                    // local_b * 4 + h
    const int b = bh >> 2;
    const int h = bh & 3;
    const int qb = qtile * 64;
    const int q0 = qb + wave * 16;
    const size_t baseTok = (size_t)b * T_SEQ;

    bf16x8 qf[4];
    {
        const ushort_t* qrow = QKV + (baseTok + q0 + (lane & 15)) * 1536 + h * 128 + (lane >> 4) * 8;
        #pragma unroll
        for (int dc = 0; dc < 4; dc++)
            qf[dc] = *(const bf16x8*)(qrow + dc * 32);
    }

    float m_run[4], l_run[4];
    f32x4 o[8];
    #pragma unroll
    for (int j = 0; j < 4; j++) { m_run[j] = -INFINITY; l_run[j] = 0.0f; }
    #pragma unroll
    for (int nt = 0; nt < 8; nt++) o[nt] = f32x4{0.f, 0.f, 0.f, 0.f};

    const int nchunks = qtile * 2 + 2;
    for (int kc = 0; kc < nchunks; kc++) {
        const int kbase = kc * 32;
        __syncthreads();
        #pragma unroll
        for (int r = 0; r < 2; r++) {
            int li = r * 256 + tid;
            int row = li >> 4;               // 0..31 key within chunk
            int c8 = (li & 15) * 8;          // 0..120 d
            size_t g = (baseTok + kbase + row) * 1536;
            uint4 vk = *(const uint4*)(QKV + g + 512 + h * 128 + c8);
            *(uint4*)(&Ks[row * 136 + c8]) = vk;
            uint4 vv = *(const uint4*)(QKV + g + 1024 + h * 128 + c8);
            ushort_t* pv = (ushort_t*)&vv;
            #pragma unroll
            for (int jj = 0; jj < 8; jj++)
                VsT[(c8 + jj) * 40 + row] = pv[jj];
        }
        __syncthreads();

        if (q0 + 15 >= kbase) {
            f32x4 s0 = {0.f,0.f,0.f,0.f}, s1 = {0.f,0.f,0.f,0.f};
            #pragma unroll
            for (int dc = 0; dc < 4; dc++) {
                bf16x8 kf0 = *(const bf16x8*)(&Ks[(lane & 15) * 136 + dc * 32 + (lane >> 4) * 8]);
                bf16x8 kf1 = *(const bf16x8*)(&Ks[(16 + (lane & 15)) * 136 + dc * 32 + (lane >> 4) * 8]);
                s0 = __builtin_amdgcn_mfma_f32_16x16x32_bf16(qf[dc], kf0, s0, 0, 0, 0);
                s1 = __builtin_amdgcn_mfma_f32_16x16x32_bf16(qf[dc], kf1, s1, 0, 0, 0);
            }
            const int key0 = kbase + (lane & 15);
            const int key1 = key0 + 16;
            float p0[4], p1[4], alpha[4];
            #pragma unroll
            for (int j = 0; j < 4; j++) {
                int qrow = q0 + (lane >> 4) * 4 + j;
                float sv0 = (key0 <= qrow) ? s0[j] * SM_SCALE : -INFINITY;
                float sv1 = (key1 <= qrow) ? s1[j] * SM_SCALE : -INFINITY;
                float mx = fmaxf(sv0, sv1);
                #pragma unroll
                for (int d = 1; d < 16; d <<= 1) mx = fmaxf(mx, __shfl_xor(mx, d));
                float mnew = fmaxf(m_run[j], mx);
                float aa = expf(m_run[j] - mnew);
                p0[j] = expf(sv0 - mnew);
                p1[j] = expf(sv1 - mnew);
                float rs = p0[j] + p1[j];
                #pragma unroll
                for (int d = 1; d < 16; d <<= 1) rs += __shfl_xor(rs, d);
                l_run[j] = l_run[j] * aa + rs;
                m_run[j] = mnew;
                alpha[j] = aa;
            }
            #pragma unroll
            for (int nt = 0; nt < 8; nt++)
                #pragma unroll
                for (int j = 0; j < 4; j++) o[nt][j] *= alpha[j];
            #pragma unroll
            for (int j = 0; j < 4; j++) {
                int rloc = (lane >> 4) * 4 + j;
                Ps[wave][rloc * 40 + (lane & 15)]      = f2bf(p0[j]);
                Ps[wave][rloc * 40 + 16 + (lane & 15)] = f2bf(p1[j]);
            }
            bf16x8 pa = *(const bf16x8*)(&Ps[wave][(lane & 15) * 40 + (lane >> 4) * 8]);
            #pragma unroll
            for (int nt = 0; nt < 8; nt++) {
                bf16x8 vf = *(const bf16x8*)(&VsT[(nt * 16 + (lane & 15)) * 40 + (lane >> 4) * 8]);
                o[nt] = __builtin_amdgcn_mfma_f32_16x16x32_bf16(pa, vf, o[nt], 0, 0, 0);
            }
        }
    }

    #pragma unroll
    for (int j = 0; j < 4; j++) {
        float inv = 1.0f / l_run[j];
        size_t row = baseTok + q0 + (lane >> 4) * 4 + j;
        #pragma unroll
        for (int nt = 0; nt < 8; nt++)
            Ao[row * 512 + h * 128 + nt * 16 + (lane & 15)] = f2bf(o[nt][j] * inv);
    }
}

// ---------------------------------------------------------------------------
extern "C" void kernel_launch(void* const* d_in, const int* in_sizes, int n_in,
                              void* d_out, int out_size, void* d_ws, size_t ws_size,
                              hipStream_t stream) {
    const float* x     = (const float*)d_in[0];
    const float* Wq    = (const float*)d_in[1];
    const float* Wk    = (const float*)d_in[2];
    const float* bk    = (const float*)d_in[3];
    const float* Wv    = (const float*)d_in[4];
    const float* Wproj = (const float*)d_in[5];
    const float* bproj = (const float*)d_in[6];
    const float* w1    = (const float*)d_in[7];
    const float* w2    = (const float*)d_in[8];
    const float* Wi    = (const float*)d_in[9];
    const float* Wo    = (const float*)d_in[10];
    float* out = (float*)d_out;   // also serves as the f32 residual/z buffer
    (void)in_sizes; (void)n_in; (void)out_size;

    char* ws = (char*)d_ws;
    size_t off = 0;
    auto alloc = [&](size_t bytes) -> void* {
        void* p = ws + off;
        off += (bytes + 255) & ~(size_t)255;
        return p;
    };
    // ---- persistent weights (prepped once per call) ----
    ushort_t* WqkvT    = (ushort_t*)alloc((size_t)1536 * 512 * 2);
    float*    bias1536 = (float*)   alloc((size_t)1536 * 4);
    ushort_t* WprojT   = (ushort_t*)alloc((size_t)512 * 512 * 2);
    ushort_t* WiT      = (ushort_t*)alloc((size_t)4096 * 512 * 2);
    ushort_t* WoT2     = (ushort_t*)alloc((size_t)512 * 4096 * 2);
    const size_t weightBytes = off;

    // ---- choose batch-chunk count so scratch fits ws_size ----
    int nchunks = 1;
    while (nchunks < 64) {
        size_t Mc = (size_t)TOKENS / nchunks;
        size_t need = weightBytes + Mc * 512 * 2 + Mc * 4096 * 2 + 4096;
        if (need <= ws_size) break;
        nchunks *= 2;
    }
    const size_t Mc = (size_t)TOKENS / nchunks;          // tokens per chunk
    const int    nbChunk = B_BATCH / nchunks;            // batches per chunk

    ushort_t* hb  = (ushort_t*)alloc(Mc * 512 * 2);      // h -> attn out -> x2 bf16 (time-shared)
    ushort_t* big = (ushort_t*)alloc(Mc * 4096 * 2);     // qkv (1536 wide) -> hmid (4096 wide)

    // ---- weight prep ----
    prep_qkv <<<(1536 * 512 + 255) / 256, 256, 0, stream>>>(Wq, Wk, Wv, WqkvT);
    prep_bias<<<6, 256, 0, stream>>>(bk, bias1536);
    prep_proj<<<1024, 256, 0, stream>>>(Wproj, WprojT);
    prep_wi  <<<8192, 256, 0, stream>>>(Wi, WiT);
    prep_wo  <<<8192, 256, 0, stream>>>(Wo, WoT2);

    for (int ck = 0; ck < nchunks; ck++) {
        const size_t t0 = (size_t)ck * Mc;
        const float* xC   = x + t0 * 512;
        float*       zC   = out + t0 * 512;
        const int    Mi   = (int)Mc;
        const int    mt   = Mi / 128;                    // 128-row M-tiles

        // h = rmsnorm(x, w1) -> hb (bf16)
        rmsnorm_kernel<<<Mi / 4, 256, 0, stream>>>(xC, w1, hb);
        // QKV = h @ WqkvT^T + bias -> big (bf16, width 1536)
        gemm128<0><<<mt * 12, 256, 0, stream>>>(
            hb, WqkvT, nullptr, big, bias1536, nullptr, nullptr, 1536, 512);
        // attention -> hb (bf16, width 512)
        attn_kernel<<<dim3(T_SEQ / 64, nbChunk * H_HEADS), 256, 0, stream>>>(big, hb);
        // z = x + attn @ Wproj + bproj -> zC (f32, lives in d_out)
        gemm128<1><<<mt * 4, 256, 0, stream>>>(
            hb, WprojT, zC, nullptr, bproj, xC, nullptr, 512, 512);
        // x2 = rmsnorm(z, w2) -> hb (bf16 only; no f32 round-trip)
        rmsnorm_kernel<<<Mi / 4, 256, 0, stream>>>(zC, w2, hb);
        // hmid = gelu(x2 @ WiT^T), both branches as N=4096 -> big
        gemm128<2><<<mt * 32, 256, 0, stream>>>(
            hb, WiT, nullptr, big, nullptr, nullptr, nullptr, 4096, 512);
        // out = x2(bf16 hb) + hmid @ WoT2^T   (0.5 folded into WoT2, K=4096)
        gemm128<3><<<mt * 4, 256, 0, stream>>>(
            big, WoT2, zC, nullptr, nullptr, nullptr, hb, 512, 4096);
    }
}

// Round 13
// 2437.846 us; speedup vs baseline: 1.2172x; 1.2172x over previous
//
#include <hip/hip_runtime.h>
#include <cstdint>
#include <cstddef>

#define TOKENS 131072      // B*T = 512*256
#define B_BATCH 512
#define T_SEQ 256
#define C_DIM 512
#define H_HEADS 4
#define HS_DIM 128
#define FF_DIM 2048
#define EPS_RMS 1e-8f
#define SM_SCALE 0.044194173824159216f   // 512^-0.5

typedef short bf16x8 __attribute__((ext_vector_type(8)));
typedef float f32x4 __attribute__((ext_vector_type(4)));
typedef unsigned short ushort_t;

__device__ __forceinline__ ushort_t f2bf(float f) {
    uint32_t u = __builtin_bit_cast(uint32_t, f);
    u += 0x7FFFu + ((u >> 16) & 1u);   // round-to-nearest-even
    return (ushort_t)(u >> 16);
}

__device__ __forceinline__ float bf2f(ushort_t u) {
    return __builtin_bit_cast(float, (uint32_t)u << 16);
}

// tanh-form GELU: |gelu_tanh - gelu_erf| <= ~3e-3 absolute; validated r7/r10/r11
// (absmax unchanged at 0.03125).
__device__ __forceinline__ float gelu_f(float x) {
    float u = 0.7978845608028654f * x + 0.035677408136300125f * (x * x * x);
    float e = __expf(2.0f * u);                 // inf-safe: e=inf -> t=1
    float t = 1.0f - 2.0f / (1.0f + e);         // tanh(u)
    return 0.5f * x * (1.0f + t);
}

// async global->LDS, 16B/lane. Dest must be wave-uniform; HW adds lane*16.
__device__ __forceinline__ void stage8k(ushort_t* lds, const ushort_t* g) {
    __builtin_amdgcn_global_load_lds(
        (const __attribute__((address_space(1))) uint32_t*)g,
        (__attribute__((address_space(3))) uint32_t*)lds,
        16, 0, 0);
}

// ---------------------------------------------------------------------------
// Weight prep: fp32 -> bf16, transposed to N x K row-major
// ---------------------------------------------------------------------------
__global__ void prep_qkv(const float* __restrict__ Wq, const float* __restrict__ Wk,
                         const float* __restrict__ Wv, ushort_t* __restrict__ WqkvT) {
    int idx = blockIdx.x * 256 + threadIdx.x;       // over 1536*512
    if (idx >= 1536 * 512) return;
    int n = idx >> 9;
    int k = idx & 511;
    int h = (n & 511) >> 7;
    int d = n & 127;
    float v;
    size_t s = ((size_t)h * 512 + k) * 128 + d;     // (H,C,HS)
    if (n < 512)       v = Wq[s];
    else if (n < 1024) v = Wk[s];
    else               v = Wv[s];
    WqkvT[idx] = f2bf(v);
}

__global__ void prep_bias(const float* __restrict__ bk, float* __restrict__ bias1536) {
    int n = blockIdx.x * 256 + threadIdx.x;
    if (n >= 1536) return;
    bias1536[n] = (n >= 512 && n < 1024) ? bk[n - 512] : 0.0f;   // bk flat (H,HS)
}

__global__ void prep_proj(const float* __restrict__ Wproj, ushort_t* __restrict__ WprojT) {
    int idx = blockIdx.x * 256 + threadIdx.x;       // over 512*512
    if (idx >= 512 * 512) return;
    int n = idx >> 9, k = idx & 511;
    WprojT[idx] = f2bf(Wproj[(size_t)k * 512 + n]);
}

__global__ void prep_wi(const float* __restrict__ Wi, ushort_t* __restrict__ WiT) {
    int idx = blockIdx.x * 256 + threadIdx.x;       // over 2*2048*512
    if (idx >= 2 * 2048 * 512) return;
    int b = idx >> 20;
    int rem = idx & 1048575;
    int f = rem >> 9, c = rem & 511;                // WiT[b*2048+f][c] = [4096][512]
    WiT[idx] = f2bf(Wi[((size_t)b * 512 + c) * 2048 + f]);
}

// WoT2[c][br*2048+f] = 0.5 * Wo[br][f][c]  -> [512][4096] row-major over K=4096
__global__ void prep_wo(const float* __restrict__ Wo, ushort_t* __restrict__ WoT2) {
    int idx = blockIdx.x * 256 + threadIdx.x;       // over 512*4096
    if (idx >= 512 * 4096) return;
    int c  = idx >> 12;
    int n2 = idx & 4095;
    int br = n2 >> 11;
    int f  = n2 & 2047;
    WoT2[idx] = f2bf(0.5f * Wo[(((size_t)br * 2048 + f) * 512) + c]);
}

// ---------------------------------------------------------------------------
// RMSNorm: one wave per token (512 floats, 8/lane); bf16 out only.
// ---------------------------------------------------------------------------
__global__ __launch_bounds__(256) void rmsnorm_kernel(const float* __restrict__ in,
                                                      const float* __restrict__ wptr,
                                                      ushort_t* __restrict__ outb) {
    const int lane = threadIdx.x & 63;
    const int wave = threadIdx.x >> 6;
    const size_t token = (size_t)blockIdx.x * 4 + wave;
    const float* row = in + token * 512;
    float4 v0 = *(const float4*)(row + lane * 8);
    float4 v1 = *(const float4*)(row + lane * 8 + 4);
    float ss = v0.x*v0.x + v0.y*v0.y + v0.z*v0.z + v0.w*v0.w
             + v1.x*v1.x + v1.y*v1.y + v1.z*v1.z + v1.w*v1.w;
    #pragma unroll
    for (int d = 32; d; d >>= 1) ss += __shfl_xor(ss, d);
    float scale = wptr[0] * rsqrtf(ss * (1.0f / 512.0f) + EPS_RMS);
    float vals[8] = {v0.x, v0.y, v0.z, v0.w, v1.x, v1.y, v1.z, v1.w};
    union { ushort_t us[8]; uint4 u4; } pk;
    #pragma unroll
    for (int i = 0; i < 8; i++) pk.us[i] = f2bf(vals[i] * scale);
    *(uint4*)(outb + token * 512 + lane * 8) = pk.u4;
}

// ---------------------------------------------------------------------------
// GEMM 256x256, BK=64, 8-phase FIFO counted-vmcnt(6), 128KB LDS.
// r13 delta vs r11: the pre-MFMA barrier of each phase is REMOVED (8 -> 4
// barriers per K-tile). Phase = {ds-load; stage-issue; lgkmcnt(0); MFMA;
// s_barrier}. This lets waves DESYNCHRONIZE within a phase: early waves run
// their MFMA cluster while late waves still drain ds_reads, keeping the
// CU-shared LDS pipe busy DURING MFMA (m114 cross-wave overlap) instead of
// strictly alternating LD-windows and MM-windows (the measured ~25% MfmaUtil
// lockstep ceiling of r5-r12).
// Hazard ledger (single end-of-phase barriers), FIFO stage order:
//   P1: LDA(b,0) LDB(b,0,bA) | stA(~b,1,t+1) | lgkm0 MM(0,0,bA) BAR
//   P2: LDB(b,1,bB)          | stA( b,0,t+2) | lgkm0 MM(0,1,bB) BAR
//   P3: LDA(b,1)             | stB( b,0,t+2) | lgkm0 MM(1,1,bB) BAR
//   P4:                      | stB( b,1,t+2) | lgkm0+vmcnt(6) MM(1,0,bA) BAR
// WAR: each stage targets a region whose last ds_read is >=1 barrier earlier
// (a wave arrives at its phase barrier only AFTER its lgkmcnt(0), so passing
// phase p's barrier proves all p-reads globally retired): A1@P1 <- read
// prev-P7; A0@P2 <- read P1; B0@P3 <- read P1; B1@P4 <- read P2; symmetric
// P5-P8. RAW: FIFO vmcnt(6) at P4/P8 keeps exactly {A0,B0,B1}(next tile) in
// flight -> all four current-tile parts drained before first read (r11
// ledger, unchanged). Prologue: 7 half-tiles FIFO + vmcnt(6) + BAR. Tail
// stages clamp SOURCE K-tile only; clamped writes land in regions never
// read again.
// MODE 0: Cb = bf16(acc + bias[c])       MODE 1: Cf = acc + bias[c] + X(f32)
// MODE 2: Cb = bf16(gelu(acc))           MODE 3: Cf = bf2f(Xb) + acc
// ---------------------------------------------------------------------------
template<int MODE>
__global__ __launch_bounds__(512) void gemm256(
    const ushort_t* __restrict__ A, const ushort_t* __restrict__ Bt,
    float* Cf, ushort_t* __restrict__ Cb,
    const float* __restrict__ bias, const float* __restrict__ X,
    const ushort_t* __restrict__ Xb,
    int N, int K)
{
    __shared__ __align__(16) ushort_t S[2][2][256 * 64];   // [buf][0=A,1=B] 128KB
    const int tid  = threadIdx.x;
    const int lane = tid & 63;
    const int wave = tid >> 6;
    const int wm = wave >> 2;          // 0..1
    const int wn = wave & 3;           // 0..3

    // XCD-chunked bijective swizzle (nwg % 8 == 0 for all our grids)
    const int nwg  = (int)gridDim.x;
    const int orig = (int)blockIdx.x;
    const int wgid = (orig & 7) * (nwg >> 3) + (orig >> 3);
    const int gx   = N >> 8;
    const int bm = (wgid / gx) << 8;
    const int bn = (wgid % gx) << 8;

    const int NT = K >> 6;             // K-tiles of 64 (NT >= 8, even, here)

    // pre-swizzled global source column (elements): granule (lane&7)^(lane>>3)
    const int sx = (((lane & 7) ^ (lane >> 3)) << 3);

    auto stA = [&](int dbuf, int part, int ts) {
        int tc = ts < NT ? ts : NT - 1;
        #pragma unroll
        for (int i = 0; i < 2; i++) {
            int rbase = i * 128 + part * 64 + wave * 8;
            stage8k(&S[dbuf][0][rbase * 64],
                    A + (size_t)(bm + rbase + (lane >> 3)) * K + tc * 64 + sx);
        }
    };
    auto stB = [&](int dbuf, int part, int ts) {
        int tc = ts < NT ? ts : NT - 1;
        #pragma unroll
        for (int i = 0; i < 2; i++) {
            int rbase = i * 128 + (wave >> 2) * 64 + part * 32 + (wave & 3) * 8;
            stage8k(&S[dbuf][1][rbase * 64],
                    Bt + (size_t)(bn + rbase + (lane >> 3)) * K + tc * 64 + sx);
        }
    };

    const int r16 = lane & 15;
    const int l7  = lane & 7;
    const int q   = lane >> 4;
    const int ge0 = ((q)     ^ l7) << 3;   // k-slice 0 granule elems
    const int ge1 = ((4 + q) ^ l7) << 3;   // k-slice 1

    f32x4 acc[8][4] = {};
    bf16x8 a[4][2], bA[2][2], bB[2][2];

#define LDA(BUF, MH) { _Pragma("unroll") for (int mf = 0; mf < 4; mf++) { \
    int R = wm * 128 + (MH) * 64 + mf * 16 + r16; \
    a[mf][0] = *(const bf16x8*)&S[BUF][0][R * 64 + ge0]; \
    a[mf][1] = *(const bf16x8*)&S[BUF][0][R * 64 + ge1]; } }
#define LDB(BUF, NH, breg) { _Pragma("unroll") for (int nf = 0; nf < 2; nf++) { \
    int R = wn * 64 + (NH) * 32 + nf * 16 + r16; \
    breg[nf][0] = *(const bf16x8*)&S[BUF][1][R * 64 + ge0]; \
    breg[nf][1] = *(const bf16x8*)&S[BUF][1][R * 64 + ge1]; } }
#define MM(MH, NH, breg) { __builtin_amdgcn_s_setprio(1); \
    _Pragma("unroll") for (int mf = 0; mf < 4; mf++) \
    _Pragma("unroll") for (int nf = 0; nf < 2; nf++) { \
        f32x4 t0 = __builtin_amdgcn_mfma_f32_16x16x32_bf16(a[mf][0], breg[nf][0], acc[(MH)*4+mf][(NH)*2+nf], 0, 0, 0); \
        acc[(MH)*4+mf][(NH)*2+nf] = __builtin_amdgcn_mfma_f32_16x16x32_bf16(a[mf][1], breg[nf][1], t0, 0, 0, 0); } \
    __builtin_amdgcn_s_setprio(0); }
#define BAR    __builtin_amdgcn_s_barrier()
#define WAITL  { asm volatile("s_waitcnt lgkmcnt(0)" ::: "memory"); __builtin_amdgcn_sched_barrier(0); }
#define WAITLV { asm volatile("s_waitcnt lgkmcnt(0)\n\ts_waitcnt vmcnt(6)" ::: "memory"); __builtin_amdgcn_sched_barrier(0); }

    // prologue: FIFO half-tiles [A0,B0,B1,A1](0) -> buf0, [A0,B0,B1](1) -> buf1
    // = 14 loads; vmcnt(6) drains all of tile0, keeps tile1's 3 halves in flight.
    stA(0, 0, 0); stB(0, 0, 0); stB(0, 1, 0); stA(0, 1, 0);
    stA(1, 0, 1); stB(1, 0, 1); stB(1, 1, 1);
    asm volatile("s_waitcnt vmcnt(6)" ::: "memory");
    __builtin_amdgcn_sched_barrier(0);
    BAR;

    const int NI = NT >> 1;
    for (int I = 0; I < NI; ++I) {
        const int t = 2 * I;
        // ---- K-tile t (buf0); single end-of-phase barriers ----
        LDA(0, 0); LDB(0, 0, bA);  stA(1, 1, t + 1);  WAITL;  MM(0, 0, bA); BAR;  // P1
        LDB(0, 1, bB);             stA(0, 0, t + 2);  WAITL;  MM(0, 1, bB); BAR;  // P2
        LDA(0, 1);                 stB(0, 0, t + 2);  WAITL;  MM(1, 1, bB); BAR;  // P3
                                   stB(0, 1, t + 2);  WAITLV; MM(1, 0, bA); BAR;  // P4
        // ---- K-tile t+1 (buf1) ----
        LDA(1, 0); LDB(1, 0, bA);  stA(0, 1, t + 2);  WAITL;  MM(0, 0, bA); BAR;  // P5
        LDB(1, 1, bB);             stA(1, 0, t + 3);  WAITL;  MM(0, 1, bB); BAR;  // P6
        LDA(1, 1);                 stB(1, 0, t + 3);  WAITL;  MM(1, 1, bB); BAR;  // P7
                                   stB(1, 1, t + 3);  WAITLV; MM(1, 0, bA); BAR;  // P8
    }
#undef LDA
#undef LDB
#undef MM
#undef BAR
#undef WAITL
#undef WAITLV

    #pragma unroll
    for (int mf = 0; mf < 8; mf++) {
        #pragma unroll
        for (int nf = 0; nf < 4; nf++) {
            #pragma unroll
            for (int j = 0; j < 4; j++) {
                int r = bm + wm * 128 + mf * 16 + (lane >> 4) * 4 + j;
                int c = bn + wn * 64 + nf * 16 + r16;
                float v = acc[mf][nf][j];
                size_t idx = (size_t)r * N + c;
                if (MODE == 0)      { Cb[idx] = f2bf(v + bias[c]); }
                else if (MODE == 1) { Cf[idx] = v + bias[c] + X[idx]; }
                else if (MODE == 2) { Cb[idx] = f2bf(gelu_f(v)); }
                else                { Cf[idx] = bf2f(Xb[idx]) + v; }
            }
        }
    }
}

// ---------------------------------------------------------------------------
// Fused causal attention, flash-style (online softmax). Unchanged.
// ---------------------------------------------------------------------------
__global__ __launch_bounds__(256) void attn_kernel(const ushort_t* __restrict__ QKV,
                                                   ushort_t* __restrict__ Ao) {
    __shared__ __align__(16) ushort_t Ks[32 * 136];
    __shared__ __align__(16) ushort_t VsT[128 * 40];
    __shared__ __align__(16) ushort_t Ps[4][16 * 40];
    const int tid  = threadIdx.x;
    const int lane = tid & 63;
    const int wave = tid >> 6;
    const int qtile = blockIdx.x;                 // 0..3
    const int bh = blockIdx.y;                    // local_b * 4 + h
    const int b = bh >> 2;
    const int h = bh & 3;
    const int qb = qtile * 64;
    const int q0 = qb + wave * 16;
    const size_t baseTok = (size_t)b * T_SEQ;

    bf16x8 qf[4];
    {
        const ushort_t* qrow = QKV + (baseTok + q0 + (lane & 15)) * 1536 + h * 128 + (lane >> 4) * 8;
        #pragma unroll
        for (int dc = 0; dc < 4; dc++)
            qf[dc] = *(const bf16x8*)(qrow + dc * 32);
    }

    float m_run[4], l_run[4];
    f32x4 o[8];
    #pragma unroll
    for (int j = 0; j < 4; j++) { m_run[j] = -INFINITY; l_run[j] = 0.0f; }
    #pragma unroll
    for (int nt = 0; nt < 8; nt++) o[nt] = f32x4{0.f, 0.f, 0.f, 0.f};

    const int nchunks = qtile * 2 + 2;
    for (int kc = 0; kc < nchunks; kc++) {
        const int kbase = kc * 32;
        __syncthreads();
        #pragma unroll
        for (int r = 0; r < 2; r++) {
            int li = r * 256 + tid;
            int row = li >> 4;               // 0..31 key within chunk
            int c8 = (li & 15) * 8;          // 0..120 d
            size_t g = (baseTok + kbase + row) * 1536;
            uint4 vk = *(const uint4*)(QKV + g + 512 + h * 128 + c8);
            *(uint4*)(&Ks[row * 136 + c8]) = vk;
            uint4 vv = *(const uint4*)(QKV + g + 1024 + h * 128 + c8);
            ushort_t* pv = (ushort_t*)&vv;
            #pragma unroll
            for (int jj = 0; jj < 8; jj++)
                VsT[(c8 + jj) * 40 + row] = pv[jj];
        }
        __syncthreads();

        if (q0 + 15 >= kbase) {
            f32x4 s0 = {0.f,0.f,0.f,0.f}, s1 = {0.f,0.f,0.f,0.f};
            #pragma unroll
            for (int dc = 0; dc < 4; dc++) {
                bf16x8 kf0 = *(const bf16x8*)(&Ks[(lane & 15) * 136 + dc * 32 + (lane >> 4) * 8]);
                bf16x8 kf1 = *(const bf16x8*)(&Ks[(16 + (lane & 15)) * 136 + dc * 32 + (lane >> 4) * 8]);
                s0 = __builtin_amdgcn_mfma_f32_16x16x32_bf16(qf[dc], kf0, s0, 0, 0, 0);
                s1 = __builtin_amdgcn_mfma_f32_16x16x32_bf16(qf[dc], kf1, s1, 0, 0, 0);
            }
            const int key0 = kbase + (lane & 15);
            const int key1 = key0 + 16;
            float p0[4], p1[4], alpha[4];
            #pragma unroll
            for (int j = 0; j < 4; j++) {
                int qrow = q0 + (lane >> 4) * 4 + j;
                float sv0 = (key0 <= qrow) ? s0[j] * SM_SCALE : -INFINITY;
                float sv1 = (key1 <= qrow) ? s1[j] * SM_SCALE : -INFINITY;
                float mx = fmaxf(sv0, sv1);
                #pragma unroll
                for (int d = 1; d < 16; d <<= 1) mx = fmaxf(mx, __shfl_xor(mx, d));
                float mnew = fmaxf(m_run[j], mx);
                float aa = expf(m_run[j] - mnew);
                p0[j] = expf(sv0 - mnew);
                p1[j] = expf(sv1 - mnew);
                float rs = p0[j] + p1[j];
                #pragma unroll
                for (int d = 1; d < 16; d <<= 1) rs += __shfl_xor(rs, d);
                l_run[j] = l_run[j] * aa + rs;
                m_run[j] = mnew;
                alpha[j] = aa;
            }
            #pragma unroll
            for (int nt = 0; nt < 8; nt++)
                #pragma unroll
                for (int j = 0; j < 4; j++) o[nt][j] *= alpha[j];
            #pragma unroll
            for (int j = 0; j < 4; j++) {
                int rloc = (lane >> 4) * 4 + j;
                Ps[wave][rloc * 40 + (lane & 15)]      = f2bf(p0[j]);
                Ps[wave][rloc * 40 + 16 + (lane & 15)] = f2bf(p1[j]);
            }
            bf16x8 pa = *(const bf16x8*)(&Ps[wave][(lane & 15) * 40 + (lane >> 4) * 8]);
            #pragma unroll
            for (int nt = 0; nt < 8; nt++) {
                bf16x8 vf = *(const bf16x8*)(&VsT[(nt * 16 + (lane & 15)) * 40 + (lane >> 4) * 8]);
                o[nt] = __builtin_amdgcn_mfma_f32_16x16x32_bf16(pa, vf, o[nt], 0, 0, 0);
            }
        }
    }

    #pragma unroll
    for (int j = 0; j < 4; j++) {
        float inv = 1.0f / l_run[j];
        size_t row = baseTok + q0 + (lane >> 4) * 4 + j;
        #pragma unroll
        for (int nt = 0; nt < 8; nt++)
            Ao[row * 512 + h * 128 + nt * 16 + (lane & 15)] = f2bf(o[nt][j] * inv);
    }
}

// ---------------------------------------------------------------------------
extern "C" void kernel_launch(void* const* d_in, const int* in_sizes, int n_in,
                              void* d_out, int out_size, void* d_ws, size_t ws_size,
                              hipStream_t stream) {
    const float* x     = (const float*)d_in[0];
    const float* Wq    = (const float*)d_in[1];
    const float* Wk    = (const float*)d_in[2];
    const float* bk    = (const float*)d_in[3];
    const float* Wv    = (const float*)d_in[4];
    const float* Wproj = (const float*)d_in[5];
    const float* bproj = (const float*)d_in[6];
    const float* w1    = (const float*)d_in[7];
    const float* w2    = (const float*)d_in[8];
    const float* Wi    = (const float*)d_in[9];
    const float* Wo    = (const float*)d_in[10];
    float* out = (float*)d_out;   // also serves as the f32 residual/z buffer
    (void)in_sizes; (void)n_in; (void)out_size;

    char* ws = (char*)d_ws;
    size_t off = 0;
    auto alloc = [&](size_t bytes) -> void* {
        void* p = ws + off;
        off += (bytes + 255) & ~(size_t)255;
        return p;
    };
    // ---- persistent weights (prepped once per call) ----
    ushort_t* WqkvT    = (ushort_t*)alloc((size_t)1536 * 512 * 2);
    float*    bias1536 = (float*)   alloc((size_t)1536 * 4);
    ushort_t* WprojT   = (ushort_t*)alloc((size_t)512 * 512 * 2);
    ushort_t* WiT      = (ushort_t*)alloc((size_t)4096 * 512 * 2);
    ushort_t* WoT2     = (ushort_t*)alloc((size_t)512 * 4096 * 2);
    const size_t weightBytes = off;

    // ---- choose batch-chunk count so scratch fits ws_size ----
    int nchunks = 1;
    while (nchunks < 64) {
        size_t Mc = (size_t)TOKENS / nchunks;
        size_t need = weightBytes + Mc * 512 * 2 + Mc * 4096 * 2 + 4096;
        if (need <= ws_size) break;
        nchunks *= 2;
    }
    const size_t Mc = (size_t)TOKENS / nchunks;          // tokens per chunk
    const int    nbChunk = B_BATCH / nchunks;            // batches per chunk

    ushort_t* hb  = (ushort_t*)alloc(Mc * 512 * 2);      // h -> attn out -> x2 bf16 (time-shared)
    ushort_t* big = (ushort_t*)alloc(Mc * 4096 * 2);     // qkv (1536 wide) -> hmid (4096 wide)

    // ---- weight prep ----
    prep_qkv <<<(1536 * 512 + 255) / 256, 256, 0, stream>>>(Wq, Wk, Wv, WqkvT);
    prep_bias<<<6, 256, 0, stream>>>(bk, bias1536);
    prep_proj<<<1024, 256, 0, stream>>>(Wproj, WprojT);
    prep_wi  <<<8192, 256, 0, stream>>>(Wi, WiT);
    prep_wo  <<<8192, 256, 0, stream>>>(Wo, WoT2);

    for (int ck = 0; ck < nchunks; ck++) {
        const size_t t0 = (size_t)ck * Mc;
        const float* xC   = x + t0 * 512;
        float*       zC   = out + t0 * 512;
        const int    Mi   = (int)Mc;
        const int    mt   = Mi / 256;                    // 256-row M-tiles

        // h = rmsnorm(x, w1) -> hb (bf16)
        rmsnorm_kernel<<<Mi / 4, 256, 0, stream>>>(xC, w1, hb);
        // QKV = h @ WqkvT^T + bias -> big (bf16, width 1536)
        gemm256<0><<<mt * 6, 512, 0, stream>>>(
            hb, WqkvT, nullptr, big, bias1536, nullptr, nullptr, 1536, 512);
        // attention -> hb (bf16, width 512)
        attn_kernel<<<dim3(T_SEQ / 64, nbChunk * H_HEADS), 256, 0, stream>>>(big, hb);
        // z = x + attn @ Wproj + bproj -> zC (f32, lives in d_out)
        gemm256<1><<<mt * 2, 512, 0, stream>>>(
            hb, WprojT, zC, nullptr, bproj, xC, nullptr, 512, 512);
        // x2 = rmsnorm(z, w2) -> hb (bf16 only; no f32 round-trip)
        rmsnorm_kernel<<<Mi / 4, 256, 0, stream>>>(zC, w2, hb);
        // hmid = gelu(x2 @ WiT^T), both branches as N=4096 -> big
        gemm256<2><<<mt * 16, 512, 0, stream>>>(
            hb, WiT, nullptr, big, nullptr, nullptr, nullptr, 4096, 512);
        // out = x2(bf16 hb) + hmid @ WoT2^T   (0.5 folded into WoT2, K=4096)
        gemm256<3><<<mt * 2, 512, 0, stream>>>(
            big, WoT2, zC, nullptr, nullptr, nullptr, hb, 512, 4096);
    }
}